// Round 1
// baseline (242.501 us; speedup 1.0000x reference)
//
#include <hip/hip_runtime.h>
#include <hip/hip_bf16.h>
#include <math.h>

// Problem constants
#define NQ   4096     // H*W
#define DIMC 256
#define NHC  8
#define NPC  8
#define HDC  32
#define HC   64
#define WC   64
#define BC   4

// ---------------------------------------------------------------------------
// GEMM 1: loc/att projections.
// C[b,n,o] = sum_c query[b,c,n] * W[o,c] + bias[o],  o in [0,192)
//   o <  128 -> loc  [b][n][128]
//   o >= 128 -> att logits [b][n][64]
// query: [B][256][4096] (n contiguous). Block tile 64n x 64o, TK=16,
// 256 threads, 4x4 microtile.
// ---------------------------------------------------------------------------
__global__ __launch_bounds__(256) void k_locatt(
    const float* __restrict__ query,
    const float* __restrict__ W_loc, const float* __restrict__ b_loc,
    const float* __restrict__ W_att, const float* __restrict__ b_att,
    float* __restrict__ loc, float* __restrict__ att) {
  __shared__ float Xs[16][68];
  __shared__ float Ws[16][68];
  const int b  = blockIdx.z;
  const int n0 = blockIdx.x * 64;
  const int o0 = blockIdx.y * 64;
  const int tid = threadIdx.x;
  const int tn = tid & 15, to = tid >> 4;
  const int lkk = tid >> 4, lnn4 = (tid & 15) * 4;   // X tile load coords
  const int wr = tid >> 2, wk = (tid & 3) * 4;       // W tile load coords
  const float* Xb = query + (size_t)b * DIMC * NQ;

  float acc[4][4] = {};
  for (int k0 = 0; k0 < DIMC; k0 += 16) {
    float4 xv = *(const float4*)(Xb + (size_t)(k0 + lkk) * NQ + n0 + lnn4);
    *(float4*)(&Xs[lkk][lnn4]) = xv;
    const int oo = o0 + wr;
    const float* Wrow = (oo < 128) ? (W_loc + (size_t)oo * DIMC)
                                   : (W_att + (size_t)(oo - 128) * DIMC);
    float4 wv = *(const float4*)(Wrow + k0 + wk);
    Ws[wk + 0][wr] = wv.x; Ws[wk + 1][wr] = wv.y;
    Ws[wk + 2][wr] = wv.z; Ws[wk + 3][wr] = wv.w;
    __syncthreads();
#pragma unroll
    for (int k = 0; k < 16; ++k) {
      float4 xa = *(const float4*)(&Xs[k][tn * 4]);
      float4 wa = *(const float4*)(&Ws[k][to * 4]);
      float xr[4] = {xa.x, xa.y, xa.z, xa.w};
      float wr4[4] = {wa.x, wa.y, wa.z, wa.w};
#pragma unroll
      for (int i = 0; i < 4; ++i)
#pragma unroll
        for (int j = 0; j < 4; ++j)
          acc[i][j] = fmaf(xr[i], wr4[j], acc[i][j]);
    }
    __syncthreads();
  }
#pragma unroll
  for (int i = 0; i < 4; ++i) {
    const int n = n0 + tn * 4 + i;
#pragma unroll
    for (int j = 0; j < 4; ++j) {
      const int o = o0 + to * 4 + j;
      if (o < 128) {
        loc[((size_t)b * NQ + n) * 128 + o] = acc[i][j] + b_loc[o];
      } else {
        att[((size_t)b * NQ + n) * 64 + (o - 128)] = acc[i][j] + b_att[o - 128];
      }
    }
  }
}

// ---------------------------------------------------------------------------
// GEMM 2: value projection, written as v[b][h][spatial][d] for sampling.
// v[b,h,n,d] = sum_c value[b,c,n] * W_val[h*32+d, c] + b_val[h*32+d]
// ---------------------------------------------------------------------------
__global__ __launch_bounds__(256) void k_vproj(
    const float* __restrict__ value,
    const float* __restrict__ W_val, const float* __restrict__ b_val,
    float* __restrict__ vproj) {
  __shared__ float Xs[16][68];
  __shared__ float Ws[16][68];
  const int b  = blockIdx.z;
  const int n0 = blockIdx.x * 64;
  const int o0 = blockIdx.y * 64;
  const int tid = threadIdx.x;
  const int tn = tid & 15, to = tid >> 4;
  const int lkk = tid >> 4, lnn4 = (tid & 15) * 4;
  const int wr = tid >> 2, wk = (tid & 3) * 4;
  const float* Xb = value + (size_t)b * DIMC * NQ;

  float acc[4][4] = {};
  for (int k0 = 0; k0 < DIMC; k0 += 16) {
    float4 xv = *(const float4*)(Xb + (size_t)(k0 + lkk) * NQ + n0 + lnn4);
    *(float4*)(&Xs[lkk][lnn4]) = xv;
    float4 wv = *(const float4*)(W_val + (size_t)(o0 + wr) * DIMC + k0 + wk);
    Ws[wk + 0][wr] = wv.x; Ws[wk + 1][wr] = wv.y;
    Ws[wk + 2][wr] = wv.z; Ws[wk + 3][wr] = wv.w;
    __syncthreads();
#pragma unroll
    for (int k = 0; k < 16; ++k) {
      float4 xa = *(const float4*)(&Xs[k][tn * 4]);
      float4 wa = *(const float4*)(&Ws[k][to * 4]);
      float xr[4] = {xa.x, xa.y, xa.z, xa.w};
      float wr4[4] = {wa.x, wa.y, wa.z, wa.w};
#pragma unroll
      for (int i = 0; i < 4; ++i)
#pragma unroll
        for (int j = 0; j < 4; ++j)
          acc[i][j] = fmaf(xr[i], wr4[j], acc[i][j]);
    }
    __syncthreads();
  }
#pragma unroll
  for (int i = 0; i < 4; ++i) {
    const int n = n0 + tn * 4 + i;
#pragma unroll
    for (int j = 0; j < 4; ++j) {
      const int o = o0 + to * 4 + j;
      const int h = o >> 5, d = o & 31;
      vproj[(((size_t)b * NHC + h) * NQ + n) * HDC + d] = acc[i][j] + b_val[o];
    }
  }
}

// ---------------------------------------------------------------------------
// Sampling: fused softmax (over 8 points) + bilinear gather + weighted sum.
// Thread = (query_local, d). Block: 8 queries x 32 channels for one (b,h).
// msda[b][n][h*32+d]
// ---------------------------------------------------------------------------
__global__ __launch_bounds__(256) void k_sample(
    const float* __restrict__ loc, const float* __restrict__ attL,
    const float* __restrict__ vproj, float* __restrict__ msda) {
  const int b = blockIdx.z, h = blockIdx.y;
  const int d  = threadIdx.x & 31;
  const int ql = threadIdx.x >> 5;           // 0..7
  const int n  = blockIdx.x * 8 + ql;
  const float* lp = loc  + ((size_t)b * NQ + n) * 128 + h * 16;
  const float* ap = attL + ((size_t)b * NQ + n) * 64  + h * 8;

  float lg[8];
  float m = -1e30f;
#pragma unroll
  for (int p = 0; p < 8; ++p) { lg[p] = ap[p]; m = fmaxf(m, lg[p]); }
  float s = 0.f;
#pragma unroll
  for (int p = 0; p < 8; ++p) { lg[p] = expf(lg[p] - m); s += lg[p]; }
  const float inv = 1.0f / s;

  const float* vb = vproj + ((size_t)b * NHC + h) * NQ * HDC + d;
  float acc = 0.f;
#pragma unroll
  for (int p = 0; p < 8; ++p) {
    const float x = lp[p * 2 + 0] * 64.0f - 0.5f;
    const float y = lp[p * 2 + 1] * 64.0f - 0.5f;
    const float x0f = floorf(x), y0f = floorf(y);
    const float wx = x - x0f, wy = y - y0f;
    const int x0 = (int)x0f, y0 = (int)y0f;
    const bool xv0 = (x0 >= 0) & (x0 < WC);
    const bool xv1 = (x0 + 1 >= 0) & (x0 + 1 < WC);
    const bool yv0 = (y0 >= 0) & (y0 < HC);
    const bool yv1 = (y0 + 1 >= 0) & (y0 + 1 < HC);
    float v00 = 0.f, v01 = 0.f, v10 = 0.f, v11 = 0.f;
    if (yv0) {
      const float* row = vb + (size_t)(y0 * WC) * HDC;
      if (xv0) v00 = row[(size_t)x0 * HDC];
      if (xv1) v01 = row[(size_t)(x0 + 1) * HDC];
    }
    if (yv1) {
      const float* row = vb + (size_t)((y0 + 1) * WC) * HDC;
      if (xv0) v10 = row[(size_t)x0 * HDC];
      if (xv1) v11 = row[(size_t)(x0 + 1) * HDC];
    }
    const float top = v00 + (v01 - v00) * wx;
    const float bot = v10 + (v11 - v10) * wx;
    acc += (lg[p] * inv) * (top + (bot - top) * wy);
  }
  msda[((size_t)b * NQ + n) * DIMC + h * HDC + d] = acc;
}

// ---------------------------------------------------------------------------
// GEMM 3: out[b,n,o] = sum_k msda[b,n,k] * W_out[o,k] + b_out[o]
// A row-major (k contiguous) -> transposed LDS staging.
// ---------------------------------------------------------------------------
__global__ __launch_bounds__(256) void k_out(
    const float* __restrict__ msda,
    const float* __restrict__ W_out, const float* __restrict__ b_out,
    float* __restrict__ out) {
  __shared__ float As[16][68];
  __shared__ float Ws[16][68];
  const int b  = blockIdx.z;
  const int n0 = blockIdx.x * 64;
  const int o0 = blockIdx.y * 64;
  const int tid = threadIdx.x;
  const int tn = tid & 15, to = tid >> 4;
  const int ar = tid >> 2, ak = (tid & 3) * 4;   // A tile load coords
  const int wr = tid >> 2, wk = (tid & 3) * 4;   // W tile load coords
  const float* Ab = msda + (size_t)b * NQ * DIMC;

  float acc[4][4] = {};
  for (int k0 = 0; k0 < DIMC; k0 += 16) {
    float4 av = *(const float4*)(Ab + (size_t)(n0 + ar) * DIMC + k0 + ak);
    As[ak + 0][ar] = av.x; As[ak + 1][ar] = av.y;
    As[ak + 2][ar] = av.z; As[ak + 3][ar] = av.w;
    float4 wv = *(const float4*)(W_out + (size_t)(o0 + wr) * DIMC + k0 + wk);
    Ws[wk + 0][wr] = wv.x; Ws[wk + 1][wr] = wv.y;
    Ws[wk + 2][wr] = wv.z; Ws[wk + 3][wr] = wv.w;
    __syncthreads();
#pragma unroll
    for (int k = 0; k < 16; ++k) {
      float4 xa = *(const float4*)(&As[k][tn * 4]);
      float4 wa = *(const float4*)(&Ws[k][to * 4]);
      float xr[4] = {xa.x, xa.y, xa.z, xa.w};
      float wr4[4] = {wa.x, wa.y, wa.z, wa.w};
#pragma unroll
      for (int i = 0; i < 4; ++i)
#pragma unroll
        for (int j = 0; j < 4; ++j)
          acc[i][j] = fmaf(xr[i], wr4[j], acc[i][j]);
    }
    __syncthreads();
  }
#pragma unroll
  for (int i = 0; i < 4; ++i) {
    const int n = n0 + tn * 4 + i;
    float4 r;
    r.x = acc[i][0] + b_out[o0 + to * 4 + 0];
    r.y = acc[i][1] + b_out[o0 + to * 4 + 1];
    r.z = acc[i][2] + b_out[o0 + to * 4 + 2];
    r.w = acc[i][3] + b_out[o0 + to * 4 + 3];
    *(float4*)(out + ((size_t)b * NQ + n) * DIMC + o0 + to * 4) = r;
  }
}

extern "C" void kernel_launch(void* const* d_in, const int* in_sizes, int n_in,
                              void* d_out, int out_size, void* d_ws, size_t ws_size,
                              hipStream_t stream) {
  const float* query = (const float*)d_in[0];
  const float* value = (const float*)d_in[1];
  const float* W_loc = (const float*)d_in[2];
  const float* b_loc = (const float*)d_in[3];
  const float* W_att = (const float*)d_in[4];
  const float* b_att = (const float*)d_in[5];
  const float* W_val = (const float*)d_in[6];
  const float* b_val = (const float*)d_in[7];
  const float* W_out = (const float*)d_in[8];
  const float* b_out = (const float*)d_in[9];
  float* out = (float*)d_out;

  float* ws    = (float*)d_ws;
  float* loc   = ws;                                   // B*NQ*128
  float* att   = loc   + (size_t)BC * NQ * 128;        // B*NQ*64
  float* vproj = att   + (size_t)BC * NQ * 64;         // B*NH*NQ*32
  float* msda  = vproj + (size_t)BC * NHC * NQ * HDC;  // B*NQ*256

  dim3 blk(256);
  k_locatt<<<dim3(NQ / 64, 3, BC), blk, 0, stream>>>(query, W_loc, b_loc, W_att, b_att, loc, att);
  k_vproj <<<dim3(NQ / 64, 4, BC), blk, 0, stream>>>(value, W_val, b_val, vproj);
  k_sample<<<dim3(NQ / 8, NHC, BC), blk, 0, stream>>>(loc, att, vproj, msda);
  k_out   <<<dim3(NQ / 64, 4, BC), blk, 0, stream>>>(msda, W_out, b_out, out);
}

// Round 3
// 156.665 us; speedup vs baseline: 1.5479x; 1.5479x over previous
//
#include <hip/hip_runtime.h>
#include <hip/hip_bf16.h>
#include <math.h>

#define NQ   4096
#define DIMC 256
#define NHC  8
#define NPC  8
#define HDC  32
#define HC   64
#define WC   64
#define BC   4

typedef __bf16 bf16x8 __attribute__((ext_vector_type(8)));
typedef __attribute__((ext_vector_type(4))) float f4;
typedef __attribute__((ext_vector_type(2))) float v2f;
typedef __attribute__((ext_vector_type(8))) short s8v;

__device__ __forceinline__ ushort f2bf(float f) {
  __hip_bfloat16 h = __float2bfloat16(f);
  union { __hip_bfloat16 h; ushort u; } c; c.h = h; return c.u;
}
__device__ __forceinline__ float bflo(unsigned u) {
  union { unsigned i; float f; } c; c.i = u << 16; return c.f;
}
__device__ __forceinline__ float bfhi(unsigned u) {
  union { unsigned i; float f; } c; c.i = u & 0xffff0000u; return c.f;
}

// ---------------------------------------------------------------------------
// GEMM 1 (fp32): loc/att projections. C[b,n,o] = sum_c q[b,c,n]*W[o,c]+bias
// Tile 128n x 64o, BK=16, 256 thr, microtile 8n x 4o (v2f packed fma).
// ---------------------------------------------------------------------------
__global__ __launch_bounds__(256) void k_locatt(
    const float* __restrict__ query,
    const float* __restrict__ W_loc, const float* __restrict__ b_loc,
    const float* __restrict__ W_att, const float* __restrict__ b_att,
    float* __restrict__ loc, float* __restrict__ att) {
  __shared__ float Xs[16][136];
  __shared__ float Ws[16][72];
  const int b  = blockIdx.z;
  const int n0 = blockIdx.x * 128;
  const int o0 = blockIdx.y * 64;
  const int tid = threadIdx.x;
  const int xk = tid >> 4, xn = (tid & 15) * 8;
  const int wo = tid >> 2, wk = (tid & 3) * 4;
  const int tn = (tid & 15) * 8;       // 8 n per thread
  const int to = (tid >> 4) * 4;       // 4 o per thread
  const float* Xb = query + (size_t)b * DIMC * NQ;
  const int oo = o0 + wo;
  const float* Wrow = (oo < 128) ? (W_loc + (size_t)oo * DIMC)
                                 : (W_att + (size_t)(oo - 128) * DIMC);

  v2f acc[8][2];
#pragma unroll
  for (int i = 0; i < 8; ++i) { acc[i][0] = (v2f)0.f; acc[i][1] = (v2f)0.f; }

  for (int k0 = 0; k0 < DIMC; k0 += 16) {
    float4 xv0 = *(const float4*)(Xb + (size_t)(k0 + xk) * NQ + n0 + xn);
    float4 xv1 = *(const float4*)(Xb + (size_t)(k0 + xk) * NQ + n0 + xn + 4);
    float4 wv  = *(const float4*)(Wrow + k0 + wk);
    __syncthreads();
    *(float4*)(&Xs[xk][xn])     = xv0;
    *(float4*)(&Xs[xk][xn + 4]) = xv1;
    Ws[wk + 0][wo] = wv.x; Ws[wk + 1][wo] = wv.y;
    Ws[wk + 2][wo] = wv.z; Ws[wk + 3][wo] = wv.w;
    __syncthreads();
#pragma unroll
    for (int k = 0; k < 16; ++k) {
      float4 xa = *(const float4*)(&Xs[k][tn]);
      float4 xb = *(const float4*)(&Xs[k][tn + 4]);
      v2f w01 = *(const v2f*)(&Ws[k][to]);
      v2f w23 = *(const v2f*)(&Ws[k][to + 2]);
      float xr[8] = {xa.x, xa.y, xa.z, xa.w, xb.x, xb.y, xb.z, xb.w};
#pragma unroll
      for (int i = 0; i < 8; ++i) {
        v2f xi = {xr[i], xr[i]};
        acc[i][0] = xi * w01 + acc[i][0];
        acc[i][1] = xi * w23 + acc[i][1];
      }
    }
  }
  const int obase = o0 + to;
  if (obase < 128) {
    float4 bias = *(const float4*)(b_loc + obase);
#pragma unroll
    for (int i = 0; i < 8; ++i) {
      const int n = n0 + tn + i;
      float4 r = {acc[i][0].x + bias.x, acc[i][0].y + bias.y,
                  acc[i][1].x + bias.z, acc[i][1].y + bias.w};
      *(float4*)(loc + ((size_t)b * NQ + n) * 128 + obase) = r;
    }
  } else {
    float4 bias = *(const float4*)(b_att + obase - 128);
#pragma unroll
    for (int i = 0; i < 8; ++i) {
      const int n = n0 + tn + i;
      float4 r = {acc[i][0].x + bias.x, acc[i][0].y + bias.y,
                  acc[i][1].x + bias.z, acc[i][1].y + bias.w};
      *(float4*)(att + ((size_t)b * NQ + n) * 64 + obase - 128) = r;
    }
  }
}

// ---------------------------------------------------------------------------
// GEMM 2 (bf16 MFMA): value projection -> vproj bf16 [b][h][n][d]
// Tile 128n x 64o, BK=32, 4 waves (2x2), per-wave 64n x 32o (4x2 frags).
// ---------------------------------------------------------------------------
#define LSTR 40
__global__ __launch_bounds__(256) void k_vproj(
    const float* __restrict__ value, const float* __restrict__ W_val,
    const float* __restrict__ b_val, ushort* __restrict__ vproj) {
  __shared__ __align__(16) ushort As[128 * LSTR];
  __shared__ __align__(16) ushort Ws[64 * LSTR];
  const int b  = blockIdx.z;
  const int n0 = blockIdx.x * 128;
  const int o0 = blockIdx.y * 64;
  const int tid = threadIdx.x;
  const int lane = tid & 63, wid = tid >> 6;
  const int wn0 = (wid & 1) * 64, wo0 = (wid >> 1) * 32;
  const int an = tid & 31;             // n (stride-1 across lanes), +32*nn
  const int ak = (tid >> 5) * 4;       // k group of 4
  const int wo = tid >> 2, wk = (tid & 3) * 8;
  const float* Xb = value + (size_t)b * DIMC * NQ;
  const int am = lane & 15, kq = (lane >> 4) * 8;

  f4 acc[4][2];
#pragma unroll
  for (int mi = 0; mi < 4; ++mi) { acc[mi][0] = (f4)0.f; acc[mi][1] = (f4)0.f; }

  for (int k0 = 0; k0 < DIMC; k0 += 32) {
    float av[4][4];
#pragma unroll
    for (int kk = 0; kk < 4; ++kk)
#pragma unroll
      for (int nn = 0; nn < 4; ++nn)
        av[kk][nn] = Xb[(size_t)(k0 + ak + kk) * NQ + n0 + an + nn * 32];
    float4 w0 = *(const float4*)(W_val + (size_t)(o0 + wo) * DIMC + k0 + wk);
    float4 w1 = *(const float4*)(W_val + (size_t)(o0 + wo) * DIMC + k0 + wk + 4);
    __syncthreads();
#pragma unroll
    for (int nn = 0; nn < 4; ++nn) {
      ushort4 pk;
      pk.x = f2bf(av[0][nn]); pk.y = f2bf(av[1][nn]);
      pk.z = f2bf(av[2][nn]); pk.w = f2bf(av[3][nn]);
      *(ushort4*)(&As[(an + nn * 32) * LSTR + ak]) = pk;
    }
    {
      ushort4 pa, pb;
      pa.x = f2bf(w0.x); pa.y = f2bf(w0.y); pa.z = f2bf(w0.z); pa.w = f2bf(w0.w);
      pb.x = f2bf(w1.x); pb.y = f2bf(w1.y); pb.z = f2bf(w1.z); pb.w = f2bf(w1.w);
      *(ushort4*)(&Ws[wo * LSTR + wk])     = pa;
      *(ushort4*)(&Ws[wo * LSTR + wk + 4]) = pb;
    }
    __syncthreads();
    bf16x8 afr[4], bfr[2];
#pragma unroll
    for (int mi = 0; mi < 4; ++mi)
      afr[mi] = *(const bf16x8*)(&As[(wn0 + mi * 16 + am) * LSTR + kq]);
#pragma unroll
    for (int oj = 0; oj < 2; ++oj)
      bfr[oj] = *(const bf16x8*)(&Ws[(wo0 + oj * 16 + am) * LSTR + kq]);
#pragma unroll
    for (int mi = 0; mi < 4; ++mi)
#pragma unroll
      for (int oj = 0; oj < 2; ++oj)
        acc[mi][oj] = __builtin_amdgcn_mfma_f32_16x16x32_bf16(
            afr[mi], bfr[oj], acc[mi][oj], 0, 0, 0);
  }
#pragma unroll
  for (int oj = 0; oj < 2; ++oj) {
    const int o = o0 + wo0 + oj * 16 + (lane & 15);
    const int h = o >> 5, d = o & 31;
    const float bias = b_val[o];
    ushort* dst = vproj + ((size_t)(b * NHC + h) * NQ) * HDC + d;
#pragma unroll
    for (int mi = 0; mi < 4; ++mi) {
      const int nb = n0 + wn0 + mi * 16 + (lane >> 4) * 4;
#pragma unroll
      for (int r = 0; r < 4; ++r)
        dst[(size_t)(nb + r) * HDC] = f2bf(acc[mi][oj][r] + bias);
    }
  }
}

// ---------------------------------------------------------------------------
// Sampling: Phase A computes softmax + bilinear coefs once per (q,p) into
// LDS; Phase B does pure bf16x4 gathers + fma. msda out bf16 [b][n][256].
// ---------------------------------------------------------------------------
__global__ __launch_bounds__(256) void k_sample(
    const float* __restrict__ loc, const float* __restrict__ attL,
    const ushort* __restrict__ vproj, ushort* __restrict__ msda) {
  __shared__ float4 Lc[32][9];
  __shared__ int4   Lo[32][9];
  const int b = blockIdx.z, h = blockIdx.y;
  const int tid = threadIdx.x;
  const int n0 = blockIdx.x * 32;
  {
    const int q = tid >> 3, p = tid & 7;
    const int n = n0 + q;
    const float lg = attL[((size_t)b * NQ + n) * 64 + h * 8 + p];
    float m = lg;
#pragma unroll
    for (int off = 1; off < 8; off <<= 1) m = fmaxf(m, __shfl_xor(m, off, 64));
    const float e = __expf(lg - m);
    float s = e;
#pragma unroll
    for (int off = 1; off < 8; off <<= 1) s += __shfl_xor(s, off, 64);
    const float w = e / s;
    const float2 xy = *(const float2*)(loc + ((size_t)b * NQ + n) * 128 + h * 16 + p * 2);
    const float x = xy.x * 64.0f - 0.5f;
    const float y = xy.y * 64.0f - 0.5f;
    const float x0f = floorf(x), y0f = floorf(y);
    const float wx = x - x0f, wy = y - y0f;
    const int x0 = (int)x0f, y0 = (int)y0f;
    const int x1 = x0 + 1, y1 = y0 + 1;
    const float fx0 = (x0 >= 0 && x0 < WC) ? 1.f : 0.f;
    const float fx1 = (x1 >= 0 && x1 < WC) ? 1.f : 0.f;
    const float fy0 = (y0 >= 0 && y0 < HC) ? 1.f : 0.f;
    const float fy1 = (y1 >= 0 && y1 < HC) ? 1.f : 0.f;
    const int cx0 = min(max(x0, 0), WC - 1), cx1 = min(max(x1, 0), WC - 1);
    const int cy0 = min(max(y0, 0), HC - 1), cy1 = min(max(y1, 0), HC - 1);
    float4 cf;
    cf.x = w * (1.f - wx) * (1.f - wy) * fx0 * fy0;
    cf.y = w * wx * (1.f - wy) * fx1 * fy0;
    cf.z = w * (1.f - wx) * wy * fx0 * fy1;
    cf.w = w * wx * wy * fx1 * fy1;
    int4 of;
    of.x = (cy0 * WC + cx0) * HDC; of.y = (cy0 * WC + cx1) * HDC;
    of.z = (cy1 * WC + cx0) * HDC; of.w = (cy1 * WC + cx1) * HDC;
    Lc[q][p] = cf; Lo[q][p] = of;
  }
  __syncthreads();
  const int q = tid >> 3, d4 = (tid & 7) * 4;
  const int n = n0 + q;
  const ushort* vb = vproj + (size_t)((b * NHC + h) * NQ) * HDC + d4;
  float a0 = 0.f, a1 = 0.f, a2 = 0.f, a3 = 0.f;
#pragma unroll
  for (int p = 0; p < 8; ++p) {
    const int4 of = Lo[q][p];
    const float4 cf = Lc[q][p];
    uint2 u00 = *(const uint2*)(vb + of.x);
    uint2 u01 = *(const uint2*)(vb + of.y);
    uint2 u10 = *(const uint2*)(vb + of.z);
    uint2 u11 = *(const uint2*)(vb + of.w);
    a0 += cf.x * bflo(u00.x) + cf.y * bflo(u01.x) + cf.z * bflo(u10.x) + cf.w * bflo(u11.x);
    a1 += cf.x * bfhi(u00.x) + cf.y * bfhi(u01.x) + cf.z * bfhi(u10.x) + cf.w * bfhi(u11.x);
    a2 += cf.x * bflo(u00.y) + cf.y * bflo(u01.y) + cf.z * bflo(u10.y) + cf.w * bflo(u11.y);
    a3 += cf.x * bfhi(u00.y) + cf.y * bfhi(u01.y) + cf.z * bfhi(u10.y) + cf.w * bfhi(u11.y);
  }
  ushort4 r;
  r.x = f2bf(a0); r.y = f2bf(a1); r.z = f2bf(a2); r.w = f2bf(a3);
  *(ushort4*)(msda + ((size_t)b * NQ + n) * DIMC + h * HDC + d4) = r;
}

// ---------------------------------------------------------------------------
// GEMM 3 (bf16 MFMA): out[b,n,o] = sum_k msda[b,n,k]*W_out[o,k] + b_out[o]
// A staging: row = tid>>1 (0..127), k half = (tid&1)*16 -> two s8v loads.
// (Round-2 bug: extra a1/a3 loads wrote LDS rows 128..191, clobbering Ws.)
// ---------------------------------------------------------------------------
__global__ __launch_bounds__(256) void k_out(
    const ushort* __restrict__ msda, const float* __restrict__ W_out,
    const float* __restrict__ b_out, float* __restrict__ out) {
  __shared__ __align__(16) ushort As[128 * LSTR];
  __shared__ __align__(16) ushort Ws[64 * LSTR];
  const int b  = blockIdx.z;
  const int n0 = blockIdx.x * 128;
  const int o0 = blockIdx.y * 64;
  const int tid = threadIdx.x;
  const int lane = tid & 63, wid = tid >> 6;
  const int wn0 = (wid & 1) * 64, wo0 = (wid >> 1) * 32;
  const int ar = tid >> 1, akh = (tid & 1) * 16;
  const int wo = tid >> 2, wk = (tid & 3) * 8;
  const int am = lane & 15, kq = (lane >> 4) * 8;
  const ushort* Ab = msda + (size_t)b * NQ * DIMC;

  f4 acc[4][2];
#pragma unroll
  for (int mi = 0; mi < 4; ++mi) { acc[mi][0] = (f4)0.f; acc[mi][1] = (f4)0.f; }

  for (int k0 = 0; k0 < DIMC; k0 += 32) {
    s8v a0 = *(const s8v*)(Ab + (size_t)(n0 + ar) * DIMC + k0 + akh);
    s8v a1 = *(const s8v*)(Ab + (size_t)(n0 + ar) * DIMC + k0 + akh + 8);
    float4 w0 = *(const float4*)(W_out + (size_t)(o0 + wo) * DIMC + k0 + wk);
    float4 w1 = *(const float4*)(W_out + (size_t)(o0 + wo) * DIMC + k0 + wk + 4);
    __syncthreads();
    *(s8v*)(&As[ar * LSTR + akh])     = a0;
    *(s8v*)(&As[ar * LSTR + akh + 8]) = a1;
    {
      ushort4 pa, pb;
      pa.x = f2bf(w0.x); pa.y = f2bf(w0.y); pa.z = f2bf(w0.z); pa.w = f2bf(w0.w);
      pb.x = f2bf(w1.x); pb.y = f2bf(w1.y); pb.z = f2bf(w1.z); pb.w = f2bf(w1.w);
      *(ushort4*)(&Ws[wo * LSTR + wk])     = pa;
      *(ushort4*)(&Ws[wo * LSTR + wk + 4]) = pb;
    }
    __syncthreads();
    bf16x8 afr[4], bfr[2];
#pragma unroll
    for (int mi = 0; mi < 4; ++mi)
      afr[mi] = *(const bf16x8*)(&As[(wn0 + mi * 16 + am) * LSTR + kq]);
#pragma unroll
    for (int oj = 0; oj < 2; ++oj)
      bfr[oj] = *(const bf16x8*)(&Ws[(wo0 + oj * 16 + am) * LSTR + kq]);
#pragma unroll
    for (int mi = 0; mi < 4; ++mi)
#pragma unroll
      for (int oj = 0; oj < 2; ++oj)
        acc[mi][oj] = __builtin_amdgcn_mfma_f32_16x16x32_bf16(
            afr[mi], bfr[oj], acc[mi][oj], 0, 0, 0);
  }
#pragma unroll
  for (int oj = 0; oj < 2; ++oj) {
    const int o = o0 + wo0 + oj * 16 + (lane & 15);
    const float bias = b_out[o];
#pragma unroll
    for (int mi = 0; mi < 4; ++mi) {
      const int nb = n0 + wn0 + mi * 16 + (lane >> 4) * 4;
#pragma unroll
      for (int r = 0; r < 4; ++r)
        out[((size_t)b * NQ + nb + r) * DIMC + o] = acc[mi][oj][r] + bias;
    }
  }
}

extern "C" void kernel_launch(void* const* d_in, const int* in_sizes, int n_in,
                              void* d_out, int out_size, void* d_ws, size_t ws_size,
                              hipStream_t stream) {
  const float* query = (const float*)d_in[0];
  const float* value = (const float*)d_in[1];
  const float* W_loc = (const float*)d_in[2];
  const float* b_loc = (const float*)d_in[3];
  const float* W_att = (const float*)d_in[4];
  const float* b_att = (const float*)d_in[5];
  const float* W_val = (const float*)d_in[6];
  const float* b_val = (const float*)d_in[7];
  const float* W_out = (const float*)d_in[8];
  const float* b_out = (const float*)d_in[9];
  float* out = (float*)d_out;

  float* ws = (float*)d_ws;
  float* loc   = ws;                                    // 4*4096*128 f32
  float* att   = loc + (size_t)BC * NQ * 128;           // 4*4096*64 f32
  ushort* vproj = (ushort*)(att + (size_t)BC * NQ * 64); // 4*8*4096*32 bf16
  ushort* msda  = vproj + (size_t)BC * NHC * NQ * HDC;   // 4*4096*256 bf16

  dim3 blk(256);
  k_locatt<<<dim3(NQ / 128, 3, BC), blk, 0, stream>>>(query, W_loc, b_loc, W_att, b_att, loc, att);
  k_vproj <<<dim3(NQ / 128, 4, BC), blk, 0, stream>>>(value, W_val, b_val, vproj);
  k_sample<<<dim3(NQ / 32, NHC, BC), blk, 0, stream>>>(loc, att, vproj, msda);
  k_out   <<<dim3(NQ / 128, 4, BC), blk, 0, stream>>>(msda, W_out, b_out, out);
}

// Round 4
// 130.730 us; speedup vs baseline: 1.8550x; 1.1984x over previous
//
#include <hip/hip_runtime.h>
#include <hip/hip_bf16.h>
#include <math.h>

#define NQ   4096
#define DIMC 256
#define NHC  8
#define NPC  8
#define HDC  32
#define HC   64
#define WC   64
#define BC   4
#define LSTR 40   // LDS row stride in ushorts (80 B: 16B-aligned, spreads banks)

typedef __bf16 bf16x8 __attribute__((ext_vector_type(8)));
typedef __attribute__((ext_vector_type(4))) float f4;
typedef __attribute__((ext_vector_type(8))) short s8v;

__device__ __forceinline__ ushort f2bf(float f) {
  __hip_bfloat16 h = __float2bfloat16(f);
  union { __hip_bfloat16 h; ushort u; } c; c.h = h; return c.u;
}
__device__ __forceinline__ float bfu2f(ushort u) {
  union { unsigned i; float f; } c; c.i = ((unsigned)u) << 16; return c.f;
}
__device__ __forceinline__ float bflo(unsigned u) {
  union { unsigned i; float f; } c; c.i = u << 16; return c.f;
}
__device__ __forceinline__ float bfhi(unsigned u) {
  union { unsigned i; float f; } c; c.i = u & 0xffff0000u; return c.f;
}

// ---------------------------------------------------------------------------
// GEMM 1: loc/att projections via SPLIT-PRECISION bf16 MFMA (3 passes:
// Ahi*Bhi + Alo*Bhi + Ahi*Blo). Residual ~2^-18 relative keeps sampling
// positions effectively fp32-accurate. Tile 64n x 64o, BK=32, pipelined.
// ---------------------------------------------------------------------------
__global__ __launch_bounds__(256) void k_locatt(
    const float* __restrict__ query,
    const float* __restrict__ W_loc, const float* __restrict__ b_loc,
    const float* __restrict__ W_att, const float* __restrict__ b_att,
    float* __restrict__ loc, float* __restrict__ att) {
  __shared__ __align__(16) ushort Ah[64 * LSTR], Al[64 * LSTR];
  __shared__ __align__(16) ushort Wh[64 * LSTR], Wl[64 * LSTR];
  const int b = blockIdx.z, n0 = blockIdx.x * 64, o0 = blockIdx.y * 64;
  const int tid = threadIdx.x, lane = tid & 63, wid = tid >> 6;
  const int wn0 = (wid & 1) * 32, wo0 = (wid >> 1) * 32;
  const int am = lane & 15, kq = (lane >> 4) * 8;
  const int an = tid & 63, ak = (tid >> 6) * 8;   // A staging: col n, 8 k's
  const int wo = tid >> 2, wk = (tid & 3) * 8;    // W staging
  const float* Xb = query + (size_t)b * DIMC * NQ + n0 + an;
  const int oo = o0 + wo;
  const float* Wrow = (oo < 128) ? (W_loc + (size_t)oo * DIMC)
                                 : (W_att + (size_t)(oo - 128) * DIMC);

  f4 acc[2][2];
#pragma unroll
  for (int mi = 0; mi < 2; ++mi) { acc[mi][0] = (f4)0.f; acc[mi][1] = (f4)0.f; }

  float ax[8];
  float4 wx0, wx1;
#pragma unroll
  for (int j = 0; j < 8; ++j) ax[j] = Xb[(size_t)(ak + j) * NQ];
  wx0 = *(const float4*)(Wrow + wk);
  wx1 = *(const float4*)(Wrow + wk + 4);

  for (int t = 0; t < 8; ++t) {
    __syncthreads();
    {
      union { ushort u[8]; s8v s; } ph, pl;
#pragma unroll
      for (int j = 0; j < 8; ++j) {
        ushort h = f2bf(ax[j]);
        ph.u[j] = h;
        pl.u[j] = f2bf(ax[j] - bfu2f(h));
      }
      *(s8v*)(&Ah[an * LSTR + ak]) = ph.s;
      *(s8v*)(&Al[an * LSTR + ak]) = pl.s;
      float wt[8] = {wx0.x, wx0.y, wx0.z, wx0.w, wx1.x, wx1.y, wx1.z, wx1.w};
      union { ushort u[8]; s8v s; } qh, ql;
#pragma unroll
      for (int j = 0; j < 8; ++j) {
        ushort h = f2bf(wt[j]);
        qh.u[j] = h;
        ql.u[j] = f2bf(wt[j] - bfu2f(h));
      }
      *(s8v*)(&Wh[wo * LSTR + wk]) = qh.s;
      *(s8v*)(&Wl[wo * LSTR + wk]) = ql.s;
    }
    if (t < 7) {
      const int k0 = (t + 1) * 32;
#pragma unroll
      for (int j = 0; j < 8; ++j) ax[j] = Xb[(size_t)(k0 + ak + j) * NQ];
      wx0 = *(const float4*)(Wrow + k0 + wk);
      wx1 = *(const float4*)(Wrow + k0 + wk + 4);
    }
    __syncthreads();
    bf16x8 ah[2], al[2], bh[2], bl[2];
#pragma unroll
    for (int mi = 0; mi < 2; ++mi) {
      ah[mi] = *(const bf16x8*)(&Ah[(wn0 + mi * 16 + am) * LSTR + kq]);
      al[mi] = *(const bf16x8*)(&Al[(wn0 + mi * 16 + am) * LSTR + kq]);
    }
#pragma unroll
    for (int oj = 0; oj < 2; ++oj) {
      bh[oj] = *(const bf16x8*)(&Wh[(wo0 + oj * 16 + am) * LSTR + kq]);
      bl[oj] = *(const bf16x8*)(&Wl[(wo0 + oj * 16 + am) * LSTR + kq]);
    }
#pragma unroll
    for (int mi = 0; mi < 2; ++mi)
#pragma unroll
      for (int oj = 0; oj < 2; ++oj) {
        acc[mi][oj] = __builtin_amdgcn_mfma_f32_16x16x32_bf16(ah[mi], bh[oj], acc[mi][oj], 0, 0, 0);
        acc[mi][oj] = __builtin_amdgcn_mfma_f32_16x16x32_bf16(al[mi], bh[oj], acc[mi][oj], 0, 0, 0);
        acc[mi][oj] = __builtin_amdgcn_mfma_f32_16x16x32_bf16(ah[mi], bl[oj], acc[mi][oj], 0, 0, 0);
      }
  }
  const bool isAtt = (o0 >= 128);
  float* dstBase = isAtt ? att : loc;
  const float* bias = isAtt ? b_att : b_loc;
  const int ostride = isAtt ? 64 : 128;
  const int ob = isAtt ? o0 - 128 : o0;
#pragma unroll
  for (int oj = 0; oj < 2; ++oj) {
    const int o = ob + wo0 + oj * 16 + am;
    const float bv = bias[o];
#pragma unroll
    for (int mi = 0; mi < 2; ++mi) {
      const int nb = n0 + wn0 + mi * 16 + (lane >> 4) * 4;
#pragma unroll
      for (int r = 0; r < 4; ++r)
        dstBase[((size_t)b * NQ + nb + r) * ostride + o] = acc[mi][oj][r] + bv;
    }
  }
}

// ---------------------------------------------------------------------------
// GEMM 2 (bf16 MFMA, pipelined): value projection -> vproj bf16 [b][h][n][d]
// Tile 64n x 64o, BK=32.
// ---------------------------------------------------------------------------
__global__ __launch_bounds__(256) void k_vproj(
    const float* __restrict__ value, const float* __restrict__ W_val,
    const float* __restrict__ b_val, ushort* __restrict__ vproj) {
  __shared__ __align__(16) ushort As[64 * LSTR];
  __shared__ __align__(16) ushort Ws[64 * LSTR];
  const int b = blockIdx.z, n0 = blockIdx.x * 64, o0 = blockIdx.y * 64;
  const int tid = threadIdx.x, lane = tid & 63, wid = tid >> 6;
  const int wn0 = (wid & 1) * 32, wo0 = (wid >> 1) * 32;
  const int am = lane & 15, kq = (lane >> 4) * 8;
  const int an = tid & 63, ak = (tid >> 6) * 8;
  const int wo = tid >> 2, wk = (tid & 3) * 8;
  const float* Xb = value + (size_t)b * DIMC * NQ + n0 + an;
  const float* Wrow = W_val + (size_t)(o0 + wo) * DIMC;

  f4 acc[2][2];
#pragma unroll
  for (int mi = 0; mi < 2; ++mi) { acc[mi][0] = (f4)0.f; acc[mi][1] = (f4)0.f; }

  float ax[8];
  float4 wx0, wx1;
#pragma unroll
  for (int j = 0; j < 8; ++j) ax[j] = Xb[(size_t)(ak + j) * NQ];
  wx0 = *(const float4*)(Wrow + wk);
  wx1 = *(const float4*)(Wrow + wk + 4);

  for (int t = 0; t < 8; ++t) {
    __syncthreads();
    {
      union { ushort u[8]; s8v s; } pa;
#pragma unroll
      for (int j = 0; j < 8; ++j) pa.u[j] = f2bf(ax[j]);
      *(s8v*)(&As[an * LSTR + ak]) = pa.s;
      float wt[8] = {wx0.x, wx0.y, wx0.z, wx0.w, wx1.x, wx1.y, wx1.z, wx1.w};
      union { ushort u[8]; s8v s; } pw;
#pragma unroll
      for (int j = 0; j < 8; ++j) pw.u[j] = f2bf(wt[j]);
      *(s8v*)(&Ws[wo * LSTR + wk]) = pw.s;
    }
    if (t < 7) {
      const int k0 = (t + 1) * 32;
#pragma unroll
      for (int j = 0; j < 8; ++j) ax[j] = Xb[(size_t)(k0 + ak + j) * NQ];
      wx0 = *(const float4*)(Wrow + k0 + wk);
      wx1 = *(const float4*)(Wrow + k0 + wk + 4);
    }
    __syncthreads();
    bf16x8 af[2], bf[2];
#pragma unroll
    for (int mi = 0; mi < 2; ++mi)
      af[mi] = *(const bf16x8*)(&As[(wn0 + mi * 16 + am) * LSTR + kq]);
#pragma unroll
    for (int oj = 0; oj < 2; ++oj)
      bf[oj] = *(const bf16x8*)(&Ws[(wo0 + oj * 16 + am) * LSTR + kq]);
#pragma unroll
    for (int mi = 0; mi < 2; ++mi)
#pragma unroll
      for (int oj = 0; oj < 2; ++oj)
        acc[mi][oj] = __builtin_amdgcn_mfma_f32_16x16x32_bf16(af[mi], bf[oj], acc[mi][oj], 0, 0, 0);
  }
#pragma unroll
  for (int oj = 0; oj < 2; ++oj) {
    const int o = o0 + wo0 + oj * 16 + am;
    const int h = o >> 5, d = o & 31;
    const float bias = b_val[o];
    ushort* dst = vproj + ((size_t)(b * NHC + h) * NQ) * HDC + d;
#pragma unroll
    for (int mi = 0; mi < 2; ++mi) {
      const int nb = n0 + wn0 + mi * 16 + (lane >> 4) * 4;
#pragma unroll
      for (int r = 0; r < 4; ++r)
        dst[(size_t)(nb + r) * HDC] = f2bf(acc[mi][oj][r] + bias);
    }
  }
}

// ---------------------------------------------------------------------------
// Sampling: Phase A computes softmax + bilinear coefs once per (q,p) into
// LDS; Phase B gathers uint4 (8 bf16 channels) per corner. 64 queries/block.
// ---------------------------------------------------------------------------
__global__ __launch_bounds__(256) void k_sample(
    const float* __restrict__ loc, const float* __restrict__ attL,
    const ushort* __restrict__ vproj, ushort* __restrict__ msda) {
  __shared__ float4 Lc[64][9];
  __shared__ int4   Lo[64][9];
  const int b = blockIdx.z, h = blockIdx.y;
  const int tid = threadIdx.x;
  const int n0 = blockIdx.x * 64;
#pragma unroll
  for (int it = 0; it < 2; ++it) {
    const int idx = it * 256 + tid;
    const int q = idx >> 3, p = idx & 7;
    const int n = n0 + q;
    const float lg = attL[((size_t)b * NQ + n) * 64 + h * 8 + p];
    float m = lg;
#pragma unroll
    for (int off = 1; off < 8; off <<= 1) m = fmaxf(m, __shfl_xor(m, off, 64));
    const float e = __expf(lg - m);
    float s = e;
#pragma unroll
    for (int off = 1; off < 8; off <<= 1) s += __shfl_xor(s, off, 64);
    const float w = e / s;
    const float2 xy = *(const float2*)(loc + ((size_t)b * NQ + n) * 128 + h * 16 + p * 2);
    const float x = xy.x * 64.0f - 0.5f;
    const float y = xy.y * 64.0f - 0.5f;
    const float x0f = floorf(x), y0f = floorf(y);
    const float wx = x - x0f, wy = y - y0f;
    const int x0 = (int)x0f, y0 = (int)y0f;
    const int x1 = x0 + 1, y1 = y0 + 1;
    const float fx0 = (x0 >= 0 && x0 < WC) ? 1.f : 0.f;
    const float fx1 = (x1 >= 0 && x1 < WC) ? 1.f : 0.f;
    const float fy0 = (y0 >= 0 && y0 < HC) ? 1.f : 0.f;
    const float fy1 = (y1 >= 0 && y1 < HC) ? 1.f : 0.f;
    const int cx0 = min(max(x0, 0), WC - 1), cx1 = min(max(x1, 0), WC - 1);
    const int cy0 = min(max(y0, 0), HC - 1), cy1 = min(max(y1, 0), HC - 1);
    float4 cf;
    cf.x = w * (1.f - wx) * (1.f - wy) * fx0 * fy0;
    cf.y = w * wx * (1.f - wy) * fx1 * fy0;
    cf.z = w * (1.f - wx) * wy * fx0 * fy1;
    cf.w = w * wx * wy * fx1 * fy1;
    int4 of;
    of.x = (cy0 * WC + cx0) * HDC; of.y = (cy0 * WC + cx1) * HDC;
    of.z = (cy1 * WC + cx0) * HDC; of.w = (cy1 * WC + cx1) * HDC;
    Lc[q][p] = cf; Lo[q][p] = of;
  }
  __syncthreads();
  const int q = tid >> 2, d8 = (tid & 3) * 8;
  const int n = n0 + q;
  const ushort* vb = vproj + (size_t)((b * NHC + h) * NQ) * HDC + d8;
  float a[8] = {};
#pragma unroll
  for (int p = 0; p < 8; ++p) {
    const int4 of = Lo[q][p];
    const float4 cf = Lc[q][p];
    const uint4 u00 = *(const uint4*)(vb + of.x);
    const uint4 u01 = *(const uint4*)(vb + of.y);
    const uint4 u10 = *(const uint4*)(vb + of.z);
    const uint4 u11 = *(const uint4*)(vb + of.w);
    const unsigned c00[4] = {u00.x, u00.y, u00.z, u00.w};
    const unsigned c01[4] = {u01.x, u01.y, u01.z, u01.w};
    const unsigned c10[4] = {u10.x, u10.y, u10.z, u10.w};
    const unsigned c11[4] = {u11.x, u11.y, u11.z, u11.w};
#pragma unroll
    for (int j = 0; j < 4; ++j) {
      a[2 * j]     += cf.x * bflo(c00[j]) + cf.y * bflo(c01[j]) + cf.z * bflo(c10[j]) + cf.w * bflo(c11[j]);
      a[2 * j + 1] += cf.x * bfhi(c00[j]) + cf.y * bfhi(c01[j]) + cf.z * bfhi(c10[j]) + cf.w * bfhi(c11[j]);
    }
  }
  union { ushort u[8]; s8v s; } r;
#pragma unroll
  for (int j = 0; j < 8; ++j) r.u[j] = f2bf(a[j]);
  *(s8v*)(msda + ((size_t)b * NQ + n) * DIMC + h * HDC + d8) = r.s;
}

// ---------------------------------------------------------------------------
// GEMM 3 (bf16 MFMA, pipelined): out = msda @ W_out^T + b_out
// msda already bf16 k-contiguous -> b128 staging, no conversion.
// ---------------------------------------------------------------------------
__global__ __launch_bounds__(256) void k_out(
    const ushort* __restrict__ msda, const float* __restrict__ W_out,
    const float* __restrict__ b_out, float* __restrict__ out) {
  __shared__ __align__(16) ushort As[64 * LSTR];
  __shared__ __align__(16) ushort Ws[64 * LSTR];
  const int b = blockIdx.z, n0 = blockIdx.x * 64, o0 = blockIdx.y * 64;
  const int tid = threadIdx.x, lane = tid & 63, wid = tid >> 6;
  const int wn0 = (wid & 1) * 32, wo0 = (wid >> 1) * 32;
  const int am = lane & 15, kq = (lane >> 4) * 8;
  const int ar = tid >> 2, akq = (tid & 3) * 8;
  const int wo = tid >> 2, wk = (tid & 3) * 8;
  const ushort* Ab = msda + ((size_t)b * NQ + n0 + ar) * DIMC + akq;
  const float* Wrow = W_out + (size_t)(o0 + wo) * DIMC;

  f4 acc[2][2];
#pragma unroll
  for (int mi = 0; mi < 2; ++mi) { acc[mi][0] = (f4)0.f; acc[mi][1] = (f4)0.f; }

  s8v aval = *(const s8v*)(Ab);
  float4 wx0 = *(const float4*)(Wrow + wk);
  float4 wx1 = *(const float4*)(Wrow + wk + 4);

  for (int t = 0; t < 8; ++t) {
    __syncthreads();
    *(s8v*)(&As[ar * LSTR + akq]) = aval;
    {
      float wt[8] = {wx0.x, wx0.y, wx0.z, wx0.w, wx1.x, wx1.y, wx1.z, wx1.w};
      union { ushort u[8]; s8v s; } pw;
#pragma unroll
      for (int j = 0; j < 8; ++j) pw.u[j] = f2bf(wt[j]);
      *(s8v*)(&Ws[wo * LSTR + wk]) = pw.s;
    }
    if (t < 7) {
      const int k0 = (t + 1) * 32;
      aval = *(const s8v*)(Ab + k0);
      wx0 = *(const float4*)(Wrow + k0 + wk);
      wx1 = *(const float4*)(Wrow + k0 + wk + 4);
    }
    __syncthreads();
    bf16x8 af[2], bf[2];
#pragma unroll
    for (int mi = 0; mi < 2; ++mi)
      af[mi] = *(const bf16x8*)(&As[(wn0 + mi * 16 + am) * LSTR + kq]);
#pragma unroll
    for (int oj = 0; oj < 2; ++oj)
      bf[oj] = *(const bf16x8*)(&Ws[(wo0 + oj * 16 + am) * LSTR + kq]);
#pragma unroll
    for (int mi = 0; mi < 2; ++mi)
#pragma unroll
      for (int oj = 0; oj < 2; ++oj)
        acc[mi][oj] = __builtin_amdgcn_mfma_f32_16x16x32_bf16(af[mi], bf[oj], acc[mi][oj], 0, 0, 0);
  }
#pragma unroll
  for (int oj = 0; oj < 2; ++oj) {
    const int o = o0 + wo0 + oj * 16 + am;
    const float bias = b_out[o];
#pragma unroll
    for (int mi = 0; mi < 2; ++mi) {
      const int nb = n0 + wn0 + mi * 16 + (lane >> 4) * 4;
#pragma unroll
      for (int r = 0; r < 4; ++r)
        out[((size_t)b * NQ + nb + r) * DIMC + o] = acc[mi][oj][r] + bias;
    }
  }
}

extern "C" void kernel_launch(void* const* d_in, const int* in_sizes, int n_in,
                              void* d_out, int out_size, void* d_ws, size_t ws_size,
                              hipStream_t stream) {
  const float* query = (const float*)d_in[0];
  const float* value = (const float*)d_in[1];
  const float* W_loc = (const float*)d_in[2];
  const float* b_loc = (const float*)d_in[3];
  const float* W_att = (const float*)d_in[4];
  const float* b_att = (const float*)d_in[5];
  const float* W_val = (const float*)d_in[6];
  const float* b_val = (const float*)d_in[7];
  const float* W_out = (const float*)d_in[8];
  const float* b_out = (const float*)d_in[9];
  float* out = (float*)d_out;

  float* ws = (float*)d_ws;
  float* loc    = ws;                                     // 4*4096*128 f32
  float* att    = loc + (size_t)BC * NQ * 128;            // 4*4096*64 f32
  ushort* vproj = (ushort*)(att + (size_t)BC * NQ * 64);  // bf16 [b][h][n][d]
  ushort* msda  = vproj + (size_t)BC * NHC * NQ * HDC;    // bf16 [b][n][256]

  dim3 blk(256);
  k_locatt<<<dim3(NQ / 64, 3, BC), blk, 0, stream>>>(query, W_loc, b_loc, W_att, b_att, loc, att);
  k_vproj <<<dim3(NQ / 64, 4, BC), blk, 0, stream>>>(value, W_val, b_val, vproj);
  k_sample<<<dim3(NQ / 64, NHC, BC), blk, 0, stream>>>(loc, att, vproj, msda);
  k_out   <<<dim3(NQ / 64, 4, BC), blk, 0, stream>>>(msda, W_out, b_out, out);
}